// Round 1
// baseline (877.829 us; speedup 1.0000x reference)
//
#include <hip/hip_runtime.h>

#define NN 100000
#define NE 3200000
#define FIN 300
#define HID 16
#define NC 10

// ---- degree / norm ----------------------------------------------------------

__global__ void k_init_deg(float* __restrict__ deg) {
    int i = blockIdx.x * blockDim.x + threadIdx.x;
    if (i < NN) deg[i] = 1.0f;   // self-loop weight
}

__global__ void k_deg(const int* __restrict__ col, const float* __restrict__ w,
                      float* __restrict__ deg) {
    int e = blockIdx.x * blockDim.x + threadIdx.x;
    if (e < NE) atomicAdd(&deg[col[e]], w[e]);
}

__global__ void k_dinv(float* __restrict__ deg) {
    int i = blockIdx.x * blockDim.x + threadIdx.x;
    if (i < NN) deg[i] = rsqrtf(deg[i]);   // deg >= 1 always
}

__global__ void k_norm(const int* __restrict__ row, const int* __restrict__ col,
                       const float* __restrict__ w, const float* __restrict__ dinv,
                       float* __restrict__ norm) {
    int e = blockIdx.x * blockDim.x + threadIdx.x;
    if (e < NE) norm[e] = dinv[row[e]] * w[e] * dinv[col[e]];
}

// ---- x @ W1 : [NN,300] x [300,16] ------------------------------------------

__global__ void k_xw(const float* __restrict__ x, const float* __restrict__ W1,
                     float* __restrict__ xw) {
    __shared__ float w1s[FIN * HID];
    for (int i = threadIdx.x; i < FIN * HID; i += blockDim.x) w1s[i] = W1[i];
    __syncthreads();
    long t = (long)blockIdx.x * blockDim.x + threadIdx.x;
    int node = (int)(t >> 4), c = (int)(t & 15);
    if (node >= NN) return;
    const float4* xr = (const float4*)(x + (long)node * FIN);  // 300 = 75 * 4
    float acc = 0.f;
    #pragma unroll 5
    for (int q = 0; q < FIN / 4; ++q) {
        float4 f = xr[q];
        int k = 4 * q;
        acc = fmaf(f.x, w1s[(k + 0) * HID + c], acc);
        acc = fmaf(f.y, w1s[(k + 1) * HID + c], acc);
        acc = fmaf(f.z, w1s[(k + 2) * HID + c], acc);
        acc = fmaf(f.w, w1s[(k + 3) * HID + c], acc);
    }
    xw[node * HID + c] = acc;
}

// ---- edge scatter: dst[col] += src[row] * norm ------------------------------

template <int D>
__global__ void k_scatter(const int* __restrict__ row, const int* __restrict__ col,
                          const float* __restrict__ norm, const float* __restrict__ src,
                          float* __restrict__ dst) {
    long t = (long)blockIdx.x * blockDim.x + threadIdx.x;
    int e = (int)(t >> 4), j = (int)(t & 15);
    if (e >= NE || j >= D) return;
    float v = src[(long)row[e] * D + j] * norm[e];
    atomicAdd(&dst[(long)col[e] * D + j], v);
}

// ---- finalize layer 1: + self-loop + bias, relu (in place on agg) ----------

__global__ void k_fin1(const float* __restrict__ xw, const float* __restrict__ dinv,
                       const float* __restrict__ b1, float* __restrict__ agg) {
    int t = blockIdx.x * blockDim.x + threadIdx.x;
    int node = t >> 4, c = t & 15;
    if (node >= NN) return;
    float di = dinv[node];
    int idx = node * HID + c;
    float v = fmaf(xw[idx], di * di, agg[idx]) + b1[c];
    agg[idx] = fmaxf(v, 0.f);
}

// ---- h @ W2 : [NN,16] x [16,10] --------------------------------------------

__global__ void k_h2(const float* __restrict__ h, const float* __restrict__ W2,
                     float* __restrict__ h2) {
    __shared__ float w2s[HID * NC];
    if (threadIdx.x < HID * NC) w2s[threadIdx.x] = W2[threadIdx.x];
    __syncthreads();
    int node = blockIdx.x * blockDim.x + threadIdx.x;
    if (node >= NN) return;
    float hr[HID];
    const float4* hp = (const float4*)(h + (long)node * HID);
    #pragma unroll
    for (int q = 0; q < 4; ++q) {
        float4 f = hp[q];
        hr[4 * q] = f.x; hr[4 * q + 1] = f.y; hr[4 * q + 2] = f.z; hr[4 * q + 3] = f.w;
    }
    float acc[NC];
    #pragma unroll
    for (int c = 0; c < NC; ++c) acc[c] = 0.f;
    #pragma unroll
    for (int k = 0; k < HID; ++k)
        #pragma unroll
        for (int c = 0; c < NC; ++c) acc[c] = fmaf(hr[k], w2s[k * NC + c], acc[c]);
    float* o = h2 + (long)node * NC;
    #pragma unroll
    for (int c = 0; c < NC; ++c) o[c] = acc[c];
}

// ---- finalize layer 2: + self-loop + bias, log_softmax ----------------------

__global__ void k_fin2(const float* __restrict__ h2, const float* __restrict__ dinv,
                       const float* __restrict__ b2, const float* __restrict__ agg,
                       float* __restrict__ out) {
    int node = blockIdx.x * blockDim.x + threadIdx.x;
    if (node >= NN) return;
    float di = dinv[node];
    float di2 = di * di;
    float v[NC];
    float m = -1e30f;
    #pragma unroll
    for (int c = 0; c < NC; ++c) {
        v[c] = fmaf(h2[node * NC + c], di2, agg[node * NC + c]) + b2[c];
        m = fmaxf(m, v[c]);
    }
    float s = 0.f;
    #pragma unroll
    for (int c = 0; c < NC; ++c) s += __expf(v[c] - m);
    float ls = __logf(s);
    float* o = out + (long)node * NC;
    #pragma unroll
    for (int c = 0; c < NC; ++c) o[c] = v[c] - m - ls;
}

// ---- launch -----------------------------------------------------------------

extern "C" void kernel_launch(void* const* d_in, const int* in_sizes, int n_in,
                              void* d_out, int out_size, void* d_ws, size_t ws_size,
                              hipStream_t stream) {
    const float* x  = (const float*)d_in[0];
    const int*   ei = (const int*)d_in[1];     // [2, E] row-major
    const float* ew = (const float*)d_in[2];
    const float* W1 = (const float*)d_in[3];
    const float* b1 = (const float*)d_in[4];
    const float* W2 = (const float*)d_in[5];
    const float* b2 = (const float*)d_in[6];
    float* out = (float*)d_out;

    float* ws   = (float*)d_ws;
    float* dinv = ws;                       // NN
    float* norm = dinv + NN;                // NE
    float* xw   = norm + NE;                // NN*HID
    float* agg1 = xw + (long)NN * HID;      // NN*HID  (becomes h after fin1)
    float* h2   = agg1 + (long)NN * HID;    // NN*NC
    float* agg2 = h2 + (long)NN * NC;       // NN*NC

    const int* row = ei;
    const int* col = ei + NE;

    hipMemsetAsync(agg1, 0, sizeof(float) * NN * HID, stream);
    hipMemsetAsync(agg2, 0, sizeof(float) * NN * NC, stream);

    k_init_deg<<<(NN + 255) / 256, 256, 0, stream>>>(dinv);
    k_deg<<<(NE + 255) / 256, 256, 0, stream>>>(col, ew, dinv);
    k_dinv<<<(NN + 255) / 256, 256, 0, stream>>>(dinv);
    k_norm<<<(NE + 255) / 256, 256, 0, stream>>>(row, col, ew, dinv, norm);

    k_xw<<<(int)(((long)NN * 16 + 255) / 256), 256, 0, stream>>>(x, W1, xw);
    k_scatter<HID><<<(int)(((long)NE * 16 + 255) / 256), 256, 0, stream>>>(row, col, norm, xw, agg1);
    k_fin1<<<(NN * 16 + 255) / 256, 256, 0, stream>>>(xw, dinv, b1, agg1);

    k_h2<<<(NN + 255) / 256, 256, 0, stream>>>(agg1, W2, h2);
    k_scatter<NC><<<(int)(((long)NE * 16 + 255) / 256), 256, 0, stream>>>(row, col, norm, h2, agg2);
    k_fin2<<<(NN + 255) / 256, 256, 0, stream>>>(h2, dinv, b2, agg2, out);
}